// Round 11
// baseline (183.618 us; speedup 1.0000x reference)
//
#include <hip/hip_runtime.h>
#include <cstddef>

// BoardModel: B=16384. out = [xf(32), a_mean(32), b2(32)] per sample, then board (3,22,12).
// MHA is degenerate (kv len 1 -> softmax==1): a_mean = out_proj(in_proj[64:96] @ b2 + b).
//
// R19 = R18 (87us) + channel-paired P1 + packed tail dots:
//   - P1 stored as f2 pairs: P1pair[k*61 + p] holds channels (2k,2k+1) at position p
//     (same 366-float footprint/region; bmi overlay unchanged).  conv1's pair-layout
//     accumulators store with 3 ds_write_b64 (was 6 b32); conv2 reads one
//     ds_read_b64 per (pair,position) -> 75 LDS reads/wave (was 150), each feeding
//     two broadcast pk_fma pairs.
//   - Tail dot4s packed: 2 v_pk_fma_f32 on float4 halves + horizontal add
//     (conv3/lfc1/vproj/oproj: ~144 -> ~72 VALU issues/wave; float4 loads kept).
//   - Kept from R18: pk_fma conv1-dense (w1d pairs) + conv2 (w2T pairs), rolled
//     loops, cb8 with b1 folded, LDS-only barriers, ballot piece pick, bitmask
//     board channels, int2 content loads.

#define BATCH 16384
#define SPB   4
#define NBLK  (BATCH / SPB)
#define RS    18
#define P1OFF  432          // P1 pairs: f2[k*61 + p], k<3, p<60 (366 floats; bmi overlays)
#define PCSOFF 800          // 16 ints
#define SS2    816          // floats per sample; 816*4 % 16 == 0
                            // tail overlays SBE: C2 192 @0, P2 48 @192, C3 64 @240,
                            // B2 32 @304, V 32 @336.

// workspace float offsets (cbg base is 16B-aligned)
#define WS_CB   0           // 2112: cb8[pcell*8 + o], b1 folded
#define WS_W1D  2112        // 150:  w1d[tap*6 + o] = w1[o*75 + tap]  (ch0 dense)
#define WS_W2T  2272        // 2400: w2T[tap*16 + o] = w2[o*150 + tap]
#define WS_TOT  4672

// LDS-only block barrier: do NOT drain vmcnt (global stores keep flowing).
#define BSYNC() asm volatile("s_waitcnt lgkmcnt(0)\ns_barrier" ::: "memory")

typedef float f2 __attribute__((ext_vector_type(2)));

// packed partial dot: acc += a.xy*b.xy + a.zw*b.zw  (2 x v_pk_fma_f32)
static __device__ __forceinline__ f2 pdot(float4 a, float4 b, f2 acc) {
  acc += f2{a.x, a.y} * f2{b.x, b.y};
  acc += f2{a.z, a.w} * f2{b.z, b.w};
  return acc;
}

// ---- prep: cb8 (bias folded) + dense-weight pair repacks ----
__global__ __launch_bounds__(256)
void prep_kernel(const float* __restrict__ w1, const float* __restrict__ b1,
                 const float* __restrict__ w2, float* __restrict__ ws)
{
  int i = blockIdx.x * 256 + threadIdx.x;
  if (i < 2112) {
    int p = i >> 3, o = i & 7;
    float acc = 0.f;
    if (o < 6) {
      acc = b1[o];
      int y0 = p / 12, x0 = p - y0 * 12;
#pragma unroll
      for (int dy = 0; dy < 5; ++dy)
#pragma unroll
        for (int dx = 0; dx < 5; ++dx) {
          int pr = y0 + dy - 2, pc = x0 + dx - 2;
          if (pr >= 0 && pr < 22 && pc >= 0 && pc < 12 &&
              (pr == 21 || pc == 0 || pc == 11)) {
            int k = dy * 5 + dx;
            acc += w1[(o * 3 + 0) * 25 + k] + w1[(o * 3 + 1) * 25 + k]
                 + w1[(o * 3 + 2) * 25 + k];
          }
        }
    }
    ws[WS_CB + i] = acc;
  } else if (i < WS_W1D + 150) {
    int idx = i - WS_W1D;               // w1d[tap*6+o] = w1[o*75 + tap] (ch0)
    int tap = idx / 6, o = idx - tap * 6;
    ws[i] = w1[o * 75 + tap];
  } else if (i >= WS_W2T && i < WS_TOT) {
    int idx = i - WS_W2T;               // w2T[tap*16+o] = w2[o*150 + tap]
    int tap = idx >> 4, o = idx & 15;
    ws[i] = w2[o * 150 + tap];
  }
}

__global__ __launch_bounds__(256, 4)
void board_model_kernel(const int* __restrict__ t,           // (B,232)
                        const int* __restrict__ piece_table, // (8,4,4,4)
                        const float* __restrict__ w1, const float* __restrict__ b1,
                        const float* __restrict__ w2, const float* __restrict__ b2w,
                        const float* __restrict__ w3, const float* __restrict__ b3,
                        const float* __restrict__ wf1, const float* __restrict__ bf1,
                        const float* __restrict__ fcw, const float* __restrict__ fcb,
                        const float* __restrict__ ipw, const float* __restrict__ ipb,
                        const float* __restrict__ opw, const float* __restrict__ opb,
                        const float* __restrict__ cbg,        // workspace (WS_*)
                        float* __restrict__ out,              // (B,96)
                        float* __restrict__ out_board)        // (B,3,22,12)
{
  __shared__ __align__(16) float scr[SPB * SS2];
  __shared__ __align__(16) float w1L[300];   // ch1/ch2 taps: [(chm*25+tap)*6 + o]

  const int tid  = threadIdx.x;
  const int lane = tid & 63;
  const int wv   = tid >> 6;          // wave id == sample slot
  const int bb   = blockIdx.x * SPB;

  for (int i = tid; i < 300; i += 256) {
    int o = i % 6, tt = i / 6, m = tt / 25, tp = tt - m * 25;
    w1L[i] = w1[(o * 3 + m + 1) * 25 + tp];
  }

  // ---------------- Phase A: per-wave board build + board output ----------------
  {
    float* W = &scr[wv * SS2];
    int*   pcs = (int*)&scr[wv * SS2 + PCSOFF];
    int*   bmi = (int*)&scr[wv * SS2 + P1OFF];   // 44 ints (Phase A only)
    const int* tr = t + (size_t)(bb + wv) * 232;

    float4* W4 = (float4*)W;
    for (int i = lane; i < 108; i += 64) W4[i] = float4{0.f, 0.f, 0.f, 0.f};
    if (lane < 44) bmi[lane] = 0;

    // content only (border handled via cb8): (r, b+1) -> SBE row r+2, col b+5
    // 210 ints at tr+22 (8B aligned); even pair offsets never cross a 10-wide row.
    {
      const int2* cp = (const int2*)(tr + 22);
      for (int v = lane; v < 105; v += 64) {
        int2 cv = cp[v];
        int i0 = v * 2;
        int r = i0 / 10, b = i0 - r * 10;
        W[(r + 2) * RS + b + 5] = (float)cv.x;
        W[(r + 2) * RS + b + 6] = (float)cv.y;
      }
    }

    // piece cells -> entry list; pieces always have exactly 4 cells -> ballot+ctz
    {
      const int* pt = piece_table + (tr[8] * 4 + tr[4]) * 16;
      int ptv = (lane < 16) ? pt[lane] : 0;
      unsigned long long bal = __ballot(ptv != 0);
      if (lane < 4) {
        unsigned x = (unsigned)bal & 0xffffu;
        for (int k = 0; k < lane; ++k) x &= x - 1;   // clear `lane` lowest set bits
        int sel = __builtin_ctz(x);
        int cy = sel >> 2, cx = sel & 3;
        int xx = cx + tr[1] - 2;
        int y  = cy + tr[2];
        int ny = y + tr[3];
        bool mask = (y >= 0) && (ny >= 0);
        bool xok  = (xx >= 0) && (xx < 10);
        bool v1 = mask && xok && (y < 21);
        bool v2 = mask && xok && (ny < 21);
        pcs[2 * lane + 0]       = v1 ? y  : -100;   // padded-board row
        pcs[2 * lane + 1]       = xx + 1;           // padded-board col
        pcs[2 * (lane + 4)]     = v2 ? ny : -100;
        pcs[2 * (lane + 4) + 1] = xx + 1;
        if (v1) atomicOr(&bmi[y],       1 << (xx + 1));
        if (v2) atomicOr(&bmi[22 + ny], 1 << (xx + 1));
      }
    }
    __builtin_amdgcn_wave_barrier();

    // board output: ch0 = border|content from SBE; ch1/2 = border | row bitmask
    float* ob = out_board + (size_t)(bb + wv) * 792;
    for (int v = lane; v < 198; v += 64) {
      int ch = v / 66, w = v - ch * 66;      // 66 float4 per channel
      int r = w / 3, c = (w - r * 3) * 4;    // c in {0,4,8}
      float val[4];
      if (ch == 0) {
#pragma unroll
        for (int d = 0; d < 4; ++d) {
          int cd = c + d;
          val[d] = (r == 21 || cd == 0 || cd == 11) ? 1.f
                 : W[(r + 2) * RS + cd + 4];
        }
      } else {
        int bits = bmi[(ch - 1) * 22 + r];
#pragma unroll
        for (int d = 0; d < 4; ++d) {
          int cd = c + d;
          val[d] = (r == 21 || cd == 0 || cd == 11 || ((bits >> cd) & 1)) ? 1.f : 0.f;
        }
      }
      *(float4*)(ob + v * 4) = float4{val[0], val[1], val[2], val[3]};
    }
  }
  BSYNC();   // guards w1L readiness (LDS only; board stores keep draining)

  // ------- Phase B: fused conv1+relu+pool1; wave = sample, lane = position <60 -------
  if (lane < 60) {
    int p = lane;
    int r = p / 6, c = p - r * 6;
    const float* Wq  = &scr[wv * SS2];
    const int*   pcs = (const int*)&scr[wv * SS2 + PCSOFF];
    const float* w1d = cbg + WS_W1D;

    // acc init from global cb8 (bias folded; 32B stride -> aligned float4+float2)
    f2 acc2[2][2][3];
#pragma unroll
    for (int i = 0; i < 2; ++i)
#pragma unroll
      for (int j = 0; j < 2; ++j) {
        int pcell = (2 * r + i) * 12 + (2 * c + j);
        float4 ca  = *(const float4*)(cbg + pcell * 8);
        float2 ca2 = *(const float2*)(cbg + pcell * 8 + 4);
        acc2[i][j][0] = f2{ca.x, ca.y};
        acc2[i][j][1] = f2{ca.z, ca.w};
        acc2[i][j][2] = f2{ca2.x, ca2.y};
      }

    // dense ch0 (600 FMA -> 300 v_pk_fma); u-loop ROLLED as R16
#pragma unroll 1
    for (int u = 0; u < 6; ++u) {
      const float* base = Wq + (2 * r + u) * RS + (2 * c + 2);
      float2 q0 = *(const float2*)(base);
      float2 q1 = *(const float2*)(base + 2);
      float2 q2 = *(const float2*)(base + 4);
      float rv[6] = {q0.x, q0.y, q1.x, q1.y, q2.x, q2.y};
#pragma unroll
      for (int i = 0; i < 2; ++i) {
        int ky = u - i;
        if (ky < 0 || ky > 4) continue;     // runtime branch (u is a loop var)
#pragma unroll
        for (int j = 0; j < 2; ++j)
#pragma unroll
          for (int kx = 0; kx < 5; ++kx) {
            float xv = rv[j + kx];
            const f2* wp = (const f2*)(w1d + (ky * 5 + kx) * 6);  // uniform -> SGPR pairs
            f2 xb = {xv, xv};
            acc2[i][j][0] += xb * wp[0];
            acc2[i][j][1] += xb * wp[1];
            acc2[i][j][2] += xb * wp[2];
          }
      }
    }

    // sparse piece taps; e-loop ROLLED; packed adds (weight==contribution, value==1)
#pragma unroll 1
    for (int e = 0; e < 8; ++e) {
      int pr = pcs[2 * e];
      if (pr < 0) continue;
      int pc = pcs[2 * e + 1];
      int chm = e >> 2;                       // 0 -> ch1, 1 -> ch2
      int dyb = pr + 2 - 2 * r;
      int dxb = pc + 2 - 2 * c;
      if (dyb < 0 || dyb > 5 || dxb < 0 || dxb > 5) continue;
#pragma unroll
      for (int i = 0; i < 2; ++i) {
        int dy = dyb - i;
        if ((unsigned)dy >= 5u) continue;
#pragma unroll
        for (int j = 0; j < 2; ++j) {
          int dx = dxb - j;
          if ((unsigned)dx >= 5u) continue;
          const f2* wp = (const f2*)(&w1L[(chm * 25 + dy * 5 + dx) * 6]);  // 8B aligned
          acc2[i][j][0] += wp[0];
          acc2[i][j][1] += wp[1];
          acc2[i][j][2] += wp[2];
        }
      }
    }

    // P1 pair store: 3 ds_write_b64 (pair layout == accumulator layout)
    f2* P1q2 = (f2*)&scr[wv * SS2 + P1OFF];
#pragma unroll
    for (int k = 0; k < 3; ++k) {
      f2 s = {0.f, 0.f};
#pragma unroll
      for (int i = 0; i < 2; ++i)
#pragma unroll
        for (int j = 0; j < 2; ++j) {
          f2 v = acc2[i][j][k];
          s.x += fmaxf(v.x, 0.f);
          s.y += fmaxf(v.y, 0.f);
        }
      P1q2[k * 61 + p] = f2{0.25f * s.x, 0.25f * s.y};
    }
  }
  BSYNC();   // P1 ready across waves (LDS only)

  // ---------------- conv2+relu: wave wvu -> out-channels [4wvu,4wvu+4), all samples ----
  const int wvu = __builtin_amdgcn_readfirstlane(wv);

  if (lane < 48) {
    int q = lane / 12, p = lane - q * 12;
    int r = p >> 1, c = p & 1;
    const f2* P1q2 = (const f2*)&scr[q * SS2 + P1OFF];
    const float* w2T = cbg + WS_W2T + 4 * wvu;   // uniform; 16B-aligned tap rows
    float4 bw = *(const float4*)(b2w + 4 * wvu);
    f2 a20 = {bw.x, bw.y};
    f2 a21 = {bw.z, bw.w};

    // channel-pair loop: one ds_read_b64 per (pair, position) -> 75 reads total
#pragma unroll 1
    for (int m = 0; m < 3; ++m) {
      const f2* pb = P1q2 + m * 61 + r * 6 + c;
      const float* wa = w2T + (size_t)((2 * m) * 25) * 16;       // ic = 2m
      const float* wb = w2T + (size_t)((2 * m + 1) * 25) * 16;   // ic = 2m+1
#pragma unroll 1
      for (int kr = 0; kr < 5; ++kr) {
#pragma unroll
        for (int kc = 0; kc < 5; ++kc) {
          f2 xv = pb[kr * 6 + kc];                 // channels 2m, 2m+1
          int toff = (kr * 5 + kc) * 16;
          const f2* wpa = (const f2*)(wa + toff);
          const f2* wpb = (const f2*)(wb + toff);
          f2 xa = {xv.x, xv.x};
          f2 xb = {xv.y, xv.y};
          a20 += xa * wpa[0];
          a21 += xa * wpa[1];
          a20 += xb * wpb[0];
          a21 += xb * wpb[1];
        }
      }
    }
    float* C2q = &scr[q * SS2];
    C2q[(4 * wvu + 0) * 12 + p] = fmaxf(a20.x, 0.f);
    C2q[(4 * wvu + 1) * 12 + p] = fmaxf(a20.y, 0.f);
    C2q[(4 * wvu + 2) * 12 + p] = fmaxf(a21.x, 0.f);
    C2q[(4 * wvu + 3) * 12 + p] = fmaxf(a21.y, 0.f);
  }
  BSYNC();   // C2 ready (LDS only)

  // ---------------- per-wave tail: wave q owns sample q ----------------
  {
    const int q = wvu;
    float* S = &scr[q * SS2];

    // pool2: one b128 per lane
    if (lane < 48) {
      int o = lane / 3, pr = lane - o * 3;
      float4 v4 = *(const float4*)(S + o * 12 + 4 * pr);
      S[192 + lane] = 0.25f * (v4.x + v4.y + v4.z + v4.w);
    }
    __builtin_amdgcn_wave_barrier();

    // conv3 (fc over 48): per-lane row of w3 as 12 float4, packed partials
    {
      int o = lane;
      const float4* w34 = (const float4*)(w3 + o * 48);
      const float4* S4  = (const float4*)(S + 192);
      f2 av = {b3[o], 0.f};
#pragma unroll 1
      for (int m = 0; m < 12; ++m)
        av = pdot(S4[m], w34[m], av);
      S[240 + o] = fmaxf(av.x + av.y, 0.f);
    }
    __builtin_amdgcn_wave_barrier();

    // lfc1: rows of wf1 as float4, packed partials; split-k halves via shfl
    {
      int j = lane & 31, h = lane >> 5;
      const float4* wf4 = (const float4*)(wf1 + j * 64 + 32 * h);
      const float4* S4  = (const float4*)(S + 240 + 32 * h);
      f2 pv = {0.f, 0.f};
#pragma unroll 1
      for (int m = 0; m < 8; ++m)
        pv = pdot(S4[m], wf4[m], pv);
      float part = pv.x + pv.y;
      part += __shfl_xor(part, 32, 64);
      if (h == 0) {
        float acc = fmaxf(bf1[j] + part, 0.f);
        S[304 + j] = acc;
        out[(size_t)(bb + q) * 96 + 64 + j] = acc;
      }
    }
    __builtin_amdgcn_wave_barrier();

    {
      int j = lane & 31;
      if (lane < 32) {
        // v-proj: rows 64..95 of ipw as float4, packed partials
        const float4* ip4 = (const float4*)(ipw + (size_t)(64 + j) * 32);
        const float4* S4  = (const float4*)(S + 304);
        f2 av = {ipb[64 + j], 0.f};
#pragma unroll 1
        for (int m = 0; m < 8; ++m)
          av = pdot(S4[m], ip4[m], av);
        S[336 + j] = av.x + av.y;
      } else {
        // xf: t row is 928B (16B aligned); fcw row is 32B
        const int4* t4 = (const int4*)(t + (size_t)(bb + q) * 232);
        int4 ta = t4[0], tb = t4[1];
        const float4* fc4 = (const float4*)(fcw + j * 8);
        float4 wa = fc4[0], wb = fc4[1];
        float acc = fcb[j]
                  + (float)ta.x * wa.x + (float)ta.y * wa.y
                  + (float)ta.z * wa.z + (float)ta.w * wa.w
                  + (float)tb.x * wb.x + (float)tb.y * wb.y
                  + (float)tb.z * wb.z + (float)tb.w * wb.w;
        out[(size_t)(bb + q) * 96 + j] = fmaxf(acc, 0.f);
      }
    }
    __builtin_amdgcn_wave_barrier();

    if (lane < 32) {
      int j = lane;
      const float4* op4 = (const float4*)(opw + j * 32);
      const float4* S4  = (const float4*)(S + 336);
      f2 av = {opb[j], 0.f};
#pragma unroll 1
      for (int m = 0; m < 8; ++m)
        av = pdot(S4[m], op4[m], av);
      out[(size_t)(bb + q) * 96 + 32 + j] = av.x + av.y;
    }
  }
}

extern "C" void kernel_launch(void* const* d_in, const int* in_sizes, int n_in,
                              void* d_out, int out_size, void* d_ws, size_t ws_size,
                              hipStream_t stream) {
  const int*   t   = (const int*)d_in[0];
  const int*   pt  = (const int*)d_in[1];
  const float* w1  = (const float*)d_in[2];
  const float* b1  = (const float*)d_in[3];
  const float* w2  = (const float*)d_in[4];
  const float* b2w = (const float*)d_in[5];
  const float* w3  = (const float*)d_in[6];
  const float* b3  = (const float*)d_in[7];
  const float* wf1 = (const float*)d_in[8];
  const float* bf1 = (const float*)d_in[9];
  const float* fcw = (const float*)d_in[10];
  const float* fcb = (const float*)d_in[11];
  // d_in[12] = emb : dead (softmax over singleton axis == 1)
  const float* ipw = (const float*)d_in[13];
  const float* ipb = (const float*)d_in[14];
  const float* opw = (const float*)d_in[15];
  const float* opb = (const float*)d_in[16];

  float* out       = (float*)d_out;
  float* out_board = out + (size_t)BATCH * 96;
  float* cbg       = (float*)d_ws;     // WS_TOT floats

  hipLaunchKernelGGL(prep_kernel, dim3(19), dim3(256), 0, stream, w1, b1, w2, cbg);
  hipLaunchKernelGGL(board_model_kernel, dim3(NBLK), dim3(256), 0, stream,
                     t, pt, w1, b1, w2, b2w, w3, b3, wf1, bf1, fcw, fcb,
                     ipw, ipb, opw, opb, cbg, out, out_board);
}

// Round 13
// 183.206 us; speedup vs baseline: 1.0022x; 1.0022x over previous
//
#include <hip/hip_runtime.h>
#include <cstddef>

// BoardModel: B=16384. out = [xf(32), a_mean(32), b2(32)] per sample, then board (3,22,12).
// MHA is degenerate (kv len 1 -> softmax==1): a_mean = out_proj(in_proj[64:96] @ b2 + b).
//
// R20 (resubmit -- previous round failed on infra, never measured)
// R20 = R18 (87us best) + packed tail dots ONLY (R19 unbundled):
//   - R19 post-mortem: channel-paired P1/conv2 regressed (+1M bank conflicts from
//     f2-stride-61 b64 reads; broadcast swizzles serialized the pk_fma chain).
//     Full revert of that piece: scalar stride-61 P1, scalar conv2 LDS reads.
//   - Kept new: tail dot4s as 2 x v_pk_fma_f32 on float4 halves + horizontal add
//     (conv3/lfc1/vproj/oproj: ~72 fewer VALU issues/wave, no new loads/layout).
//   - Kept from R18: pk_fma conv1-dense (w1d pairs) + conv2 (w2T pairs), rolled
//     loops, cb8 with b1 folded, LDS-only barriers, ballot piece pick, bitmask
//     board channels, int2 content loads.

#define BATCH 16384
#define SPB   4
#define NBLK  (BATCH / SPB)
#define RS    18
#define P1OFF  432          // P1: [o*61 + p], p<60 (bmi overlays this in Phase A)
#define PCSOFF 800          // 16 ints
#define SS2    816          // floats per sample; 816*4 % 16 == 0
                            // tail overlays SBE: C2 192 @0, P2 48 @192, C3 64 @240,
                            // B2 32 @304, V 32 @336.

// workspace float offsets (cbg base is 16B-aligned)
#define WS_CB   0           // 2112: cb8[pcell*8 + o], b1 folded
#define WS_W1D  2112        // 150:  w1d[tap*6 + o] = w1[o*75 + tap]  (ch0 dense)
#define WS_W2T  2272        // 2400: w2T[tap*16 + o] = w2[o*150 + tap]
#define WS_TOT  4672

// LDS-only block barrier: do NOT drain vmcnt (global stores keep flowing).
#define BSYNC() asm volatile("s_waitcnt lgkmcnt(0)\ns_barrier" ::: "memory")

typedef float f2 __attribute__((ext_vector_type(2)));

// packed partial dot: acc += a.xy*b.xy + a.zw*b.zw  (2 x v_pk_fma_f32)
static __device__ __forceinline__ f2 pdot(float4 a, float4 b, f2 acc) {
  acc += f2{a.x, a.y} * f2{b.x, b.y};
  acc += f2{a.z, a.w} * f2{b.z, b.w};
  return acc;
}

// ---- prep: cb8 (bias folded) + dense-weight pair repacks ----
__global__ __launch_bounds__(256)
void prep_kernel(const float* __restrict__ w1, const float* __restrict__ b1,
                 const float* __restrict__ w2, float* __restrict__ ws)
{
  int i = blockIdx.x * 256 + threadIdx.x;
  if (i < 2112) {
    int p = i >> 3, o = i & 7;
    float acc = 0.f;
    if (o < 6) {
      acc = b1[o];
      int y0 = p / 12, x0 = p - y0 * 12;
#pragma unroll
      for (int dy = 0; dy < 5; ++dy)
#pragma unroll
        for (int dx = 0; dx < 5; ++dx) {
          int pr = y0 + dy - 2, pc = x0 + dx - 2;
          if (pr >= 0 && pr < 22 && pc >= 0 && pc < 12 &&
              (pr == 21 || pc == 0 || pc == 11)) {
            int k = dy * 5 + dx;
            acc += w1[(o * 3 + 0) * 25 + k] + w1[(o * 3 + 1) * 25 + k]
                 + w1[(o * 3 + 2) * 25 + k];
          }
        }
    }
    ws[WS_CB + i] = acc;
  } else if (i < WS_W1D + 150) {
    int idx = i - WS_W1D;               // w1d[tap*6+o] = w1[o*75 + tap] (ch0)
    int tap = idx / 6, o = idx - tap * 6;
    ws[i] = w1[o * 75 + tap];
  } else if (i >= WS_W2T && i < WS_TOT) {
    int idx = i - WS_W2T;               // w2T[tap*16+o] = w2[o*150 + tap]
    int tap = idx >> 4, o = idx & 15;
    ws[i] = w2[o * 150 + tap];
  }
}

__global__ __launch_bounds__(256, 4)
void board_model_kernel(const int* __restrict__ t,           // (B,232)
                        const int* __restrict__ piece_table, // (8,4,4,4)
                        const float* __restrict__ w1, const float* __restrict__ b1,
                        const float* __restrict__ w2, const float* __restrict__ b2w,
                        const float* __restrict__ w3, const float* __restrict__ b3,
                        const float* __restrict__ wf1, const float* __restrict__ bf1,
                        const float* __restrict__ fcw, const float* __restrict__ fcb,
                        const float* __restrict__ ipw, const float* __restrict__ ipb,
                        const float* __restrict__ opw, const float* __restrict__ opb,
                        const float* __restrict__ cbg,        // workspace (WS_*)
                        float* __restrict__ out,              // (B,96)
                        float* __restrict__ out_board)        // (B,3,22,12)
{
  __shared__ __align__(16) float scr[SPB * SS2];
  __shared__ __align__(16) float w1L[300];   // ch1/ch2 taps: [(chm*25+tap)*6 + o]

  const int tid  = threadIdx.x;
  const int lane = tid & 63;
  const int wv   = tid >> 6;          // wave id == sample slot
  const int bb   = blockIdx.x * SPB;

  for (int i = tid; i < 300; i += 256) {
    int o = i % 6, tt = i / 6, m = tt / 25, tp = tt - m * 25;
    w1L[i] = w1[(o * 3 + m + 1) * 25 + tp];
  }

  // ---------------- Phase A: per-wave board build + board output ----------------
  {
    float* W = &scr[wv * SS2];
    int*   pcs = (int*)&scr[wv * SS2 + PCSOFF];
    int*   bmi = (int*)&scr[wv * SS2 + P1OFF];   // 44 ints (Phase A only)
    const int* tr = t + (size_t)(bb + wv) * 232;

    float4* W4 = (float4*)W;
    for (int i = lane; i < 108; i += 64) W4[i] = float4{0.f, 0.f, 0.f, 0.f};
    if (lane < 44) bmi[lane] = 0;

    // content only (border handled via cb8): (r, b+1) -> SBE row r+2, col b+5
    // 210 ints at tr+22 (8B aligned); even pair offsets never cross a 10-wide row.
    {
      const int2* cp = (const int2*)(tr + 22);
      for (int v = lane; v < 105; v += 64) {
        int2 cv = cp[v];
        int i0 = v * 2;
        int r = i0 / 10, b = i0 - r * 10;
        W[(r + 2) * RS + b + 5] = (float)cv.x;
        W[(r + 2) * RS + b + 6] = (float)cv.y;
      }
    }

    // piece cells -> entry list; pieces always have exactly 4 cells -> ballot+ctz
    {
      const int* pt = piece_table + (tr[8] * 4 + tr[4]) * 16;
      int ptv = (lane < 16) ? pt[lane] : 0;
      unsigned long long bal = __ballot(ptv != 0);
      if (lane < 4) {
        unsigned x = (unsigned)bal & 0xffffu;
        for (int k = 0; k < lane; ++k) x &= x - 1;   // clear `lane` lowest set bits
        int sel = __builtin_ctz(x);
        int cy = sel >> 2, cx = sel & 3;
        int xx = cx + tr[1] - 2;
        int y  = cy + tr[2];
        int ny = y + tr[3];
        bool mask = (y >= 0) && (ny >= 0);
        bool xok  = (xx >= 0) && (xx < 10);
        bool v1 = mask && xok && (y < 21);
        bool v2 = mask && xok && (ny < 21);
        pcs[2 * lane + 0]       = v1 ? y  : -100;   // padded-board row
        pcs[2 * lane + 1]       = xx + 1;           // padded-board col
        pcs[2 * (lane + 4)]     = v2 ? ny : -100;
        pcs[2 * (lane + 4) + 1] = xx + 1;
        if (v1) atomicOr(&bmi[y],       1 << (xx + 1));
        if (v2) atomicOr(&bmi[22 + ny], 1 << (xx + 1));
      }
    }
    __builtin_amdgcn_wave_barrier();

    // board output: ch0 = border|content from SBE; ch1/2 = border | row bitmask
    float* ob = out_board + (size_t)(bb + wv) * 792;
    for (int v = lane; v < 198; v += 64) {
      int ch = v / 66, w = v - ch * 66;      // 66 float4 per channel
      int r = w / 3, c = (w - r * 3) * 4;    // c in {0,4,8}
      float val[4];
      if (ch == 0) {
#pragma unroll
        for (int d = 0; d < 4; ++d) {
          int cd = c + d;
          val[d] = (r == 21 || cd == 0 || cd == 11) ? 1.f
                 : W[(r + 2) * RS + cd + 4];
        }
      } else {
        int bits = bmi[(ch - 1) * 22 + r];
#pragma unroll
        for (int d = 0; d < 4; ++d) {
          int cd = c + d;
          val[d] = (r == 21 || cd == 0 || cd == 11 || ((bits >> cd) & 1)) ? 1.f : 0.f;
        }
      }
      *(float4*)(ob + v * 4) = float4{val[0], val[1], val[2], val[3]};
    }
  }
  BSYNC();   // guards w1L readiness (LDS only; board stores keep draining)

  // ------- Phase B: fused conv1+relu+pool1; wave = sample, lane = position <60 -------
  if (lane < 60) {
    int p = lane;
    int r = p / 6, c = p - r * 6;
    const float* Wq  = &scr[wv * SS2];
    const int*   pcs = (const int*)&scr[wv * SS2 + PCSOFF];
    const float* w1d = cbg + WS_W1D;

    // acc init from global cb8 (bias folded; 32B stride -> aligned float4+float2)
    f2 acc2[2][2][3];
#pragma unroll
    for (int i = 0; i < 2; ++i)
#pragma unroll
      for (int j = 0; j < 2; ++j) {
        int pcell = (2 * r + i) * 12 + (2 * c + j);
        float4 ca  = *(const float4*)(cbg + pcell * 8);
        float2 ca2 = *(const float2*)(cbg + pcell * 8 + 4);
        acc2[i][j][0] = f2{ca.x, ca.y};
        acc2[i][j][1] = f2{ca.z, ca.w};
        acc2[i][j][2] = f2{ca2.x, ca2.y};
      }

    // dense ch0 (600 FMA -> 300 v_pk_fma); u-loop ROLLED as R16
#pragma unroll 1
    for (int u = 0; u < 6; ++u) {
      const float* base = Wq + (2 * r + u) * RS + (2 * c + 2);
      float2 q0 = *(const float2*)(base);
      float2 q1 = *(const float2*)(base + 2);
      float2 q2 = *(const float2*)(base + 4);
      float rv[6] = {q0.x, q0.y, q1.x, q1.y, q2.x, q2.y};
#pragma unroll
      for (int i = 0; i < 2; ++i) {
        int ky = u - i;
        if (ky < 0 || ky > 4) continue;     // runtime branch (u is a loop var)
#pragma unroll
        for (int j = 0; j < 2; ++j)
#pragma unroll
          for (int kx = 0; kx < 5; ++kx) {
            float xv = rv[j + kx];
            const f2* wp = (const f2*)(w1d + (ky * 5 + kx) * 6);  // uniform -> SGPR pairs
            f2 xb = {xv, xv};
            acc2[i][j][0] += xb * wp[0];
            acc2[i][j][1] += xb * wp[1];
            acc2[i][j][2] += xb * wp[2];
          }
      }
    }

    // sparse piece taps; e-loop ROLLED; packed adds (weight==contribution, value==1)
#pragma unroll 1
    for (int e = 0; e < 8; ++e) {
      int pr = pcs[2 * e];
      if (pr < 0) continue;
      int pc = pcs[2 * e + 1];
      int chm = e >> 2;                       // 0 -> ch1, 1 -> ch2
      int dyb = pr + 2 - 2 * r;
      int dxb = pc + 2 - 2 * c;
      if (dyb < 0 || dyb > 5 || dxb < 0 || dxb > 5) continue;
#pragma unroll
      for (int i = 0; i < 2; ++i) {
        int dy = dyb - i;
        if ((unsigned)dy >= 5u) continue;
#pragma unroll
        for (int j = 0; j < 2; ++j) {
          int dx = dxb - j;
          if ((unsigned)dx >= 5u) continue;
          const f2* wp = (const f2*)(&w1L[(chm * 25 + dy * 5 + dx) * 6]);  // 8B aligned
          acc2[i][j][0] += wp[0];
          acc2[i][j][1] += wp[1];
          acc2[i][j][2] += wp[2];
        }
      }
    }

    float* P1q = &scr[wv * SS2 + P1OFF];
#pragma unroll
    for (int k = 0; k < 3; ++k) {
      f2 s = {0.f, 0.f};
#pragma unroll
      for (int i = 0; i < 2; ++i)
#pragma unroll
        for (int j = 0; j < 2; ++j) {
          f2 v = acc2[i][j][k];
          s.x += fmaxf(v.x, 0.f);
          s.y += fmaxf(v.y, 0.f);
        }
      P1q[(2 * k + 0) * 61 + p] = 0.25f * s.x;
      P1q[(2 * k + 1) * 61 + p] = 0.25f * s.y;
    }
  }
  BSYNC();   // P1 ready across waves (LDS only)

  // ---------------- conv2+relu: wave wvu -> out-channels [4wvu,4wvu+4), all samples ----
  const int wvu = __builtin_amdgcn_readfirstlane(wv);

  if (lane < 48) {
    int q = lane / 12, p = lane - q * 12;
    int r = p >> 1, c = p & 1;
    const float* P1q = &scr[q * SS2 + P1OFF];
    const float* w2T = cbg + WS_W2T + 4 * wvu;   // uniform; 16B-aligned tap rows
    float4 bw = *(const float4*)(b2w + 4 * wvu);
    f2 a20 = {bw.x, bw.y};
    f2 a21 = {bw.z, bw.w};

    // DOUBLE-rolled (ic x kr); per tap: 1 ds_read_b32 + s_load pairs + 2 pk_fma
#pragma unroll 1
    for (int ic = 0; ic < 6; ++ic) {
      const float* pb = P1q + ic * 61 + r * 6 + c;
#pragma unroll 1
      for (int kr = 0; kr < 5; ++kr) {
#pragma unroll
        for (int kc = 0; kc < 5; ++kc) {
          float xv = pb[kr * 6 + kc];
          const f2* wp = (const f2*)(w2T + (size_t)(ic * 25 + kr * 5 + kc) * 16);
          f2 xb = {xv, xv};
          a20 += xb * wp[0];
          a21 += xb * wp[1];
        }
      }
    }
    float* C2q = &scr[q * SS2];
    C2q[(4 * wvu + 0) * 12 + p] = fmaxf(a20.x, 0.f);
    C2q[(4 * wvu + 1) * 12 + p] = fmaxf(a20.y, 0.f);
    C2q[(4 * wvu + 2) * 12 + p] = fmaxf(a21.x, 0.f);
    C2q[(4 * wvu + 3) * 12 + p] = fmaxf(a21.y, 0.f);
  }
  BSYNC();   // C2 ready (LDS only)

  // ---------------- per-wave tail: wave q owns sample q ----------------
  {
    const int q = wvu;
    float* S = &scr[q * SS2];

    // pool2: one b128 per lane
    if (lane < 48) {
      int o = lane / 3, pr = lane - o * 3;
      float4 v4 = *(const float4*)(S + o * 12 + 4 * pr);
      S[192 + lane] = 0.25f * (v4.x + v4.y + v4.z + v4.w);
    }
    __builtin_amdgcn_wave_barrier();

    // conv3 (fc over 48): per-lane row of w3 as 12 float4, packed partials
    {
      int o = lane;
      const float4* w34 = (const float4*)(w3 + o * 48);
      const float4* S4  = (const float4*)(S + 192);
      f2 av = {b3[o], 0.f};
#pragma unroll 1
      for (int m = 0; m < 12; ++m)
        av = pdot(S4[m], w34[m], av);
      S[240 + o] = fmaxf(av.x + av.y, 0.f);
    }
    __builtin_amdgcn_wave_barrier();

    // lfc1: rows of wf1 as float4, packed partials; split-k halves via shfl
    {
      int j = lane & 31, h = lane >> 5;
      const float4* wf4 = (const float4*)(wf1 + j * 64 + 32 * h);
      const float4* S4  = (const float4*)(S + 240 + 32 * h);
      f2 pv = {0.f, 0.f};
#pragma unroll 1
      for (int m = 0; m < 8; ++m)
        pv = pdot(S4[m], wf4[m], pv);
      float part = pv.x + pv.y;
      part += __shfl_xor(part, 32, 64);
      if (h == 0) {
        float acc = fmaxf(bf1[j] + part, 0.f);
        S[304 + j] = acc;
        out[(size_t)(bb + q) * 96 + 64 + j] = acc;
      }
    }
    __builtin_amdgcn_wave_barrier();

    {
      int j = lane & 31;
      if (lane < 32) {
        // v-proj: rows 64..95 of ipw as float4, packed partials
        const float4* ip4 = (const float4*)(ipw + (size_t)(64 + j) * 32);
        const float4* S4  = (const float4*)(S + 304);
        f2 av = {ipb[64 + j], 0.f};
#pragma unroll 1
        for (int m = 0; m < 8; ++m)
          av = pdot(S4[m], ip4[m], av);
        S[336 + j] = av.x + av.y;
      } else {
        // xf: t row is 928B (16B aligned); fcw row is 32B
        const int4* t4 = (const int4*)(t + (size_t)(bb + q) * 232);
        int4 ta = t4[0], tb = t4[1];
        const float4* fc4 = (const float4*)(fcw + j * 8);
        float4 wa = fc4[0], wb = fc4[1];
        float acc = fcb[j]
                  + (float)ta.x * wa.x + (float)ta.y * wa.y
                  + (float)ta.z * wa.z + (float)ta.w * wa.w
                  + (float)tb.x * wb.x + (float)tb.y * wb.y
                  + (float)tb.z * wb.z + (float)tb.w * wb.w;
        out[(size_t)(bb + q) * 96 + j] = fmaxf(acc, 0.f);
      }
    }
    __builtin_amdgcn_wave_barrier();

    if (lane < 32) {
      int j = lane;
      const float4* op4 = (const float4*)(opw + j * 32);
      const float4* S4  = (const float4*)(S + 336);
      f2 av = {opb[j], 0.f};
#pragma unroll 1
      for (int m = 0; m < 8; ++m)
        av = pdot(S4[m], op4[m], av);
      out[(size_t)(bb + q) * 96 + 32 + j] = av.x + av.y;
    }
  }
}

extern "C" void kernel_launch(void* const* d_in, const int* in_sizes, int n_in,
                              void* d_out, int out_size, void* d_ws, size_t ws_size,
                              hipStream_t stream) {
  const int*   t   = (const int*)d_in[0];
  const int*   pt  = (const int*)d_in[1];
  const float* w1  = (const float*)d_in[2];
  const float* b1  = (const float*)d_in[3];
  const float* w2  = (const float*)d_in[4];
  const float* b2w = (const float*)d_in[5];
  const float* w3  = (const float*)d_in[6];
  const float* b3  = (const float*)d_in[7];
  const float* wf1 = (const float*)d_in[8];
  const float* bf1 = (const float*)d_in[9];
  const float* fcw = (const float*)d_in[10];
  const float* fcb = (const float*)d_in[11];
  // d_in[12] = emb : dead (softmax over singleton axis == 1)
  const float* ipw = (const float*)d_in[13];
  const float* ipb = (const float*)d_in[14];
  const float* opw = (const float*)d_in[15];
  const float* opb = (const float*)d_in[16];

  float* out       = (float*)d_out;
  float* out_board = out + (size_t)BATCH * 96;
  float* cbg       = (float*)d_ws;     // WS_TOT floats

  hipLaunchKernelGGL(prep_kernel, dim3(19), dim3(256), 0, stream, w1, b1, w2, cbg);
  hipLaunchKernelGGL(board_model_kernel, dim3(NBLK), dim3(256), 0, stream,
                     t, pt, w1, b1, w2, b2w, w3, b3, wf1, bf1, fcw, fcb,
                     ipw, ipb, opw, opb, cbg, out, out_board);
}

// Round 14
// 182.451 us; speedup vs baseline: 1.0064x; 1.0041x over previous
//
#include <hip/hip_runtime.h>
#include <cstddef>

// BoardModel: B=16384. out = [xf(32), a_mean(32), b2(32)] per sample, then board (3,22,12).
// MHA is degenerate (kv len 1 -> softmax==1): a_mean = out_proj(in_proj[64:96] @ b2 + b).
//
// R21 = R20 (87.8us) + occupancy hint + board-out b64 reads:
//   - OccupancyPercent stuck at ~76% (24 waves/CU) though nothing caps below 32:
//     LDS 14.3KB -> 11 blocks, VGPR 24 -> no cap.  launch_bounds(256,4) only asks
//     for 4 blocks/CU.  Request 8 (VGPR cap 64 >= 24, no spill risk) -> +33% TLP
//     against the exposed-latency floor.
//   - board-output ch0: 2 x ds_read_b64 (offset (r+2)*18+c+4 always even) instead
//     of 4 x ds_read_b32; border overrides applied after the load.
//   - R19/R20 bank lesson kept: conv2 stays scalar o-major stride-61 (48 lanes ->
//     24 distinct banks, 2-way = free); channel-paired layouts concentrate banks
//     (~12-way) and lose.
//   - Kept from R18/R20: pk_fma conv1-dense (w1d pairs) + conv2 (w2T pairs),
//     packed tail dots, rolled loops, cb8 with b1 folded, LDS-only barriers,
//     ballot piece pick, bitmask board channels, int2 content loads.

#define BATCH 16384
#define SPB   4
#define NBLK  (BATCH / SPB)
#define RS    18
#define P1OFF  432          // P1: [o*61 + p], p<60 (bmi overlays this in Phase A)
#define PCSOFF 800          // 16 ints
#define SS2    816          // floats per sample; 816*4 % 16 == 0
                            // tail overlays SBE: C2 192 @0, P2 48 @192, C3 64 @240,
                            // B2 32 @304, V 32 @336.

// workspace float offsets (cbg base is 16B-aligned)
#define WS_CB   0           // 2112: cb8[pcell*8 + o], b1 folded
#define WS_W1D  2112        // 150:  w1d[tap*6 + o] = w1[o*75 + tap]  (ch0 dense)
#define WS_W2T  2272        // 2400: w2T[tap*16 + o] = w2[o*150 + tap]
#define WS_TOT  4672

// LDS-only block barrier: do NOT drain vmcnt (global stores keep flowing).
#define BSYNC() asm volatile("s_waitcnt lgkmcnt(0)\ns_barrier" ::: "memory")

typedef float f2 __attribute__((ext_vector_type(2)));

// packed partial dot: acc += a.xy*b.xy + a.zw*b.zw  (2 x v_pk_fma_f32)
static __device__ __forceinline__ f2 pdot(float4 a, float4 b, f2 acc) {
  acc += f2{a.x, a.y} * f2{b.x, b.y};
  acc += f2{a.z, a.w} * f2{b.z, b.w};
  return acc;
}

// ---- prep: cb8 (bias folded) + dense-weight pair repacks ----
__global__ __launch_bounds__(256)
void prep_kernel(const float* __restrict__ w1, const float* __restrict__ b1,
                 const float* __restrict__ w2, float* __restrict__ ws)
{
  int i = blockIdx.x * 256 + threadIdx.x;
  if (i < 2112) {
    int p = i >> 3, o = i & 7;
    float acc = 0.f;
    if (o < 6) {
      acc = b1[o];
      int y0 = p / 12, x0 = p - y0 * 12;
#pragma unroll
      for (int dy = 0; dy < 5; ++dy)
#pragma unroll
        for (int dx = 0; dx < 5; ++dx) {
          int pr = y0 + dy - 2, pc = x0 + dx - 2;
          if (pr >= 0 && pr < 22 && pc >= 0 && pc < 12 &&
              (pr == 21 || pc == 0 || pc == 11)) {
            int k = dy * 5 + dx;
            acc += w1[(o * 3 + 0) * 25 + k] + w1[(o * 3 + 1) * 25 + k]
                 + w1[(o * 3 + 2) * 25 + k];
          }
        }
    }
    ws[WS_CB + i] = acc;
  } else if (i < WS_W1D + 150) {
    int idx = i - WS_W1D;               // w1d[tap*6+o] = w1[o*75 + tap] (ch0)
    int tap = idx / 6, o = idx - tap * 6;
    ws[i] = w1[o * 75 + tap];
  } else if (i >= WS_W2T && i < WS_TOT) {
    int idx = i - WS_W2T;               // w2T[tap*16+o] = w2[o*150 + tap]
    int tap = idx >> 4, o = idx & 15;
    ws[i] = w2[o * 150 + tap];
  }
}

__global__ __launch_bounds__(256, 8)
void board_model_kernel(const int* __restrict__ t,           // (B,232)
                        const int* __restrict__ piece_table, // (8,4,4,4)
                        const float* __restrict__ w1, const float* __restrict__ b1,
                        const float* __restrict__ w2, const float* __restrict__ b2w,
                        const float* __restrict__ w3, const float* __restrict__ b3,
                        const float* __restrict__ wf1, const float* __restrict__ bf1,
                        const float* __restrict__ fcw, const float* __restrict__ fcb,
                        const float* __restrict__ ipw, const float* __restrict__ ipb,
                        const float* __restrict__ opw, const float* __restrict__ opb,
                        const float* __restrict__ cbg,        // workspace (WS_*)
                        float* __restrict__ out,              // (B,96)
                        float* __restrict__ out_board)        // (B,3,22,12)
{
  __shared__ __align__(16) float scr[SPB * SS2];
  __shared__ __align__(16) float w1L[300];   // ch1/ch2 taps: [(chm*25+tap)*6 + o]

  const int tid  = threadIdx.x;
  const int lane = tid & 63;
  const int wv   = tid >> 6;          // wave id == sample slot
  const int bb   = blockIdx.x * SPB;

  for (int i = tid; i < 300; i += 256) {
    int o = i % 6, tt = i / 6, m = tt / 25, tp = tt - m * 25;
    w1L[i] = w1[(o * 3 + m + 1) * 25 + tp];
  }

  // ---------------- Phase A: per-wave board build + board output ----------------
  {
    float* W = &scr[wv * SS2];
    int*   pcs = (int*)&scr[wv * SS2 + PCSOFF];
    int*   bmi = (int*)&scr[wv * SS2 + P1OFF];   // 44 ints (Phase A only)
    const int* tr = t + (size_t)(bb + wv) * 232;

    float4* W4 = (float4*)W;
    for (int i = lane; i < 108; i += 64) W4[i] = float4{0.f, 0.f, 0.f, 0.f};
    if (lane < 44) bmi[lane] = 0;

    // content only (border handled via cb8): (r, b+1) -> SBE row r+2, col b+5
    // 210 ints at tr+22 (8B aligned); even pair offsets never cross a 10-wide row.
    {
      const int2* cp = (const int2*)(tr + 22);
      for (int v = lane; v < 105; v += 64) {
        int2 cv = cp[v];
        int i0 = v * 2;
        int r = i0 / 10, b = i0 - r * 10;
        W[(r + 2) * RS + b + 5] = (float)cv.x;
        W[(r + 2) * RS + b + 6] = (float)cv.y;
      }
    }

    // piece cells -> entry list; pieces always have exactly 4 cells -> ballot+ctz
    {
      const int* pt = piece_table + (tr[8] * 4 + tr[4]) * 16;
      int ptv = (lane < 16) ? pt[lane] : 0;
      unsigned long long bal = __ballot(ptv != 0);
      if (lane < 4) {
        unsigned x = (unsigned)bal & 0xffffu;
        for (int k = 0; k < lane; ++k) x &= x - 1;   // clear `lane` lowest set bits
        int sel = __builtin_ctz(x);
        int cy = sel >> 2, cx = sel & 3;
        int xx = cx + tr[1] - 2;
        int y  = cy + tr[2];
        int ny = y + tr[3];
        bool mask = (y >= 0) && (ny >= 0);
        bool xok  = (xx >= 0) && (xx < 10);
        bool v1 = mask && xok && (y < 21);
        bool v2 = mask && xok && (ny < 21);
        pcs[2 * lane + 0]       = v1 ? y  : -100;   // padded-board row
        pcs[2 * lane + 1]       = xx + 1;           // padded-board col
        pcs[2 * (lane + 4)]     = v2 ? ny : -100;
        pcs[2 * (lane + 4) + 1] = xx + 1;
        if (v1) atomicOr(&bmi[y],       1 << (xx + 1));
        if (v2) atomicOr(&bmi[22 + ny], 1 << (xx + 1));
      }
    }
    __builtin_amdgcn_wave_barrier();

    // board output: ch0 = border|content from SBE; ch1/2 = border | row bitmask
    float* ob = out_board + (size_t)(bb + wv) * 792;
    for (int v = lane; v < 198; v += 64) {
      int ch = v / 66, w = v - ch * 66;      // 66 float4 per channel
      int r = w / 3, c = (w - r * 3) * 4;    // c in {0,4,8}
      float val[4];
      if (ch == 0) {
        // (r+2)*RS + c + 4 is always even -> two aligned b64 reads; overrides after
        float2 va = *(const float2*)(&W[(r + 2) * RS + c + 4]);
        float2 vb = *(const float2*)(&W[(r + 2) * RS + c + 6]);
        val[0] = va.x; val[1] = va.y; val[2] = vb.x; val[3] = vb.y;
        if (r == 21) { val[0] = val[1] = val[2] = val[3] = 1.f; }
        else {
          if (c == 0) val[0] = 1.f;       // cd == 0
          if (c == 8) val[3] = 1.f;       // cd == 11
        }
      } else {
        int bits = bmi[(ch - 1) * 22 + r];
#pragma unroll
        for (int d = 0; d < 4; ++d) {
          int cd = c + d;
          val[d] = (r == 21 || cd == 0 || cd == 11 || ((bits >> cd) & 1)) ? 1.f : 0.f;
        }
      }
      *(float4*)(ob + v * 4) = float4{val[0], val[1], val[2], val[3]};
    }
  }
  BSYNC();   // guards w1L readiness (LDS only; board stores keep draining)

  // ------- Phase B: fused conv1+relu+pool1; wave = sample, lane = position <60 -------
  if (lane < 60) {
    int p = lane;
    int r = p / 6, c = p - r * 6;
    const float* Wq  = &scr[wv * SS2];
    const int*   pcs = (const int*)&scr[wv * SS2 + PCSOFF];
    const float* w1d = cbg + WS_W1D;

    // acc init from global cb8 (bias folded; 32B stride -> aligned float4+float2)
    f2 acc2[2][2][3];
#pragma unroll
    for (int i = 0; i < 2; ++i)
#pragma unroll
      for (int j = 0; j < 2; ++j) {
        int pcell = (2 * r + i) * 12 + (2 * c + j);
        float4 ca  = *(const float4*)(cbg + pcell * 8);
        float2 ca2 = *(const float2*)(cbg + pcell * 8 + 4);
        acc2[i][j][0] = f2{ca.x, ca.y};
        acc2[i][j][1] = f2{ca.z, ca.w};
        acc2[i][j][2] = f2{ca2.x, ca2.y};
      }

    // dense ch0 (600 FMA -> 300 v_pk_fma); u-loop ROLLED as R16
#pragma unroll 1
    for (int u = 0; u < 6; ++u) {
      const float* base = Wq + (2 * r + u) * RS + (2 * c + 2);
      float2 q0 = *(const float2*)(base);
      float2 q1 = *(const float2*)(base + 2);
      float2 q2 = *(const float2*)(base + 4);
      float rv[6] = {q0.x, q0.y, q1.x, q1.y, q2.x, q2.y};
#pragma unroll
      for (int i = 0; i < 2; ++i) {
        int ky = u - i;
        if (ky < 0 || ky > 4) continue;     // runtime branch (u is a loop var)
#pragma unroll
        for (int j = 0; j < 2; ++j)
#pragma unroll
          for (int kx = 0; kx < 5; ++kx) {
            float xv = rv[j + kx];
            const f2* wp = (const f2*)(w1d + (ky * 5 + kx) * 6);  // uniform -> SGPR pairs
            f2 xb = {xv, xv};
            acc2[i][j][0] += xb * wp[0];
            acc2[i][j][1] += xb * wp[1];
            acc2[i][j][2] += xb * wp[2];
          }
      }
    }

    // sparse piece taps; e-loop ROLLED; packed adds (weight==contribution, value==1)
#pragma unroll 1
    for (int e = 0; e < 8; ++e) {
      int pr = pcs[2 * e];
      if (pr < 0) continue;
      int pc = pcs[2 * e + 1];
      int chm = e >> 2;                       // 0 -> ch1, 1 -> ch2
      int dyb = pr + 2 - 2 * r;
      int dxb = pc + 2 - 2 * c;
      if (dyb < 0 || dyb > 5 || dxb < 0 || dxb > 5) continue;
#pragma unroll
      for (int i = 0; i < 2; ++i) {
        int dy = dyb - i;
        if ((unsigned)dy >= 5u) continue;
#pragma unroll
        for (int j = 0; j < 2; ++j) {
          int dx = dxb - j;
          if ((unsigned)dx >= 5u) continue;
          const f2* wp = (const f2*)(&w1L[(chm * 25 + dy * 5 + dx) * 6]);  // 8B aligned
          acc2[i][j][0] += wp[0];
          acc2[i][j][1] += wp[1];
          acc2[i][j][2] += wp[2];
        }
      }
    }

    float* P1q = &scr[wv * SS2 + P1OFF];
#pragma unroll
    for (int k = 0; k < 3; ++k) {
      f2 s = {0.f, 0.f};
#pragma unroll
      for (int i = 0; i < 2; ++i)
#pragma unroll
        for (int j = 0; j < 2; ++j) {
          f2 v = acc2[i][j][k];
          s.x += fmaxf(v.x, 0.f);
          s.y += fmaxf(v.y, 0.f);
        }
      P1q[(2 * k + 0) * 61 + p] = 0.25f * s.x;
      P1q[(2 * k + 1) * 61 + p] = 0.25f * s.y;
    }
  }
  BSYNC();   // P1 ready across waves (LDS only)

  // ---------------- conv2+relu: wave wvu -> out-channels [4wvu,4wvu+4), all samples ----
  const int wvu = __builtin_amdgcn_readfirstlane(wv);

  if (lane < 48) {
    int q = lane / 12, p = lane - q * 12;
    int r = p >> 1, c = p & 1;
    const float* P1q = &scr[q * SS2 + P1OFF];
    const float* w2T = cbg + WS_W2T + 4 * wvu;   // uniform; 16B-aligned tap rows
    float4 bw = *(const float4*)(b2w + 4 * wvu);
    f2 a20 = {bw.x, bw.y};
    f2 a21 = {bw.z, bw.w};

    // DOUBLE-rolled (ic x kr); per tap: 1 ds_read_b32 + s_load pairs + 2 pk_fma
#pragma unroll 1
    for (int ic = 0; ic < 6; ++ic) {
      const float* pb = P1q + ic * 61 + r * 6 + c;
#pragma unroll 1
      for (int kr = 0; kr < 5; ++kr) {
#pragma unroll
        for (int kc = 0; kc < 5; ++kc) {
          float xv = pb[kr * 6 + kc];
          const f2* wp = (const f2*)(w2T + (size_t)(ic * 25 + kr * 5 + kc) * 16);
          f2 xb = {xv, xv};
          a20 += xb * wp[0];
          a21 += xb * wp[1];
        }
      }
    }
    float* C2q = &scr[q * SS2];
    C2q[(4 * wvu + 0) * 12 + p] = fmaxf(a20.x, 0.f);
    C2q[(4 * wvu + 1) * 12 + p] = fmaxf(a20.y, 0.f);
    C2q[(4 * wvu + 2) * 12 + p] = fmaxf(a21.x, 0.f);
    C2q[(4 * wvu + 3) * 12 + p] = fmaxf(a21.y, 0.f);
  }
  BSYNC();   // C2 ready (LDS only)

  // ---------------- per-wave tail: wave q owns sample q ----------------
  {
    const int q = wvu;
    float* S = &scr[q * SS2];

    // pool2: one b128 per lane
    if (lane < 48) {
      int o = lane / 3, pr = lane - o * 3;
      float4 v4 = *(const float4*)(S + o * 12 + 4 * pr);
      S[192 + lane] = 0.25f * (v4.x + v4.y + v4.z + v4.w);
    }
    __builtin_amdgcn_wave_barrier();

    // conv3 (fc over 48): per-lane row of w3 as 12 float4, packed partials
    {
      int o = lane;
      const float4* w34 = (const float4*)(w3 + o * 48);
      const float4* S4  = (const float4*)(S + 192);
      f2 av = {b3[o], 0.f};
#pragma unroll 1
      for (int m = 0; m < 12; ++m)
        av = pdot(S4[m], w34[m], av);
      S[240 + o] = fmaxf(av.x + av.y, 0.f);
    }
    __builtin_amdgcn_wave_barrier();

    // lfc1: rows of wf1 as float4, packed partials; split-k halves via shfl
    {
      int j = lane & 31, h = lane >> 5;
      const float4* wf4 = (const float4*)(wf1 + j * 64 + 32 * h);
      const float4* S4  = (const float4*)(S + 240 + 32 * h);
      f2 pv = {0.f, 0.f};
#pragma unroll 1
      for (int m = 0; m < 8; ++m)
        pv = pdot(S4[m], wf4[m], pv);
      float part = pv.x + pv.y;
      part += __shfl_xor(part, 32, 64);
      if (h == 0) {
        float acc = fmaxf(bf1[j] + part, 0.f);
        S[304 + j] = acc;
        out[(size_t)(bb + q) * 96 + 64 + j] = acc;
      }
    }
    __builtin_amdgcn_wave_barrier();

    {
      int j = lane & 31;
      if (lane < 32) {
        // v-proj: rows 64..95 of ipw as float4, packed partials
        const float4* ip4 = (const float4*)(ipw + (size_t)(64 + j) * 32);
        const float4* S4  = (const float4*)(S + 304);
        f2 av = {ipb[64 + j], 0.f};
#pragma unroll 1
        for (int m = 0; m < 8; ++m)
          av = pdot(S4[m], ip4[m], av);
        S[336 + j] = av.x + av.y;
      } else {
        // xf: t row is 928B (16B aligned); fcw row is 32B
        const int4* t4 = (const int4*)(t + (size_t)(bb + q) * 232);
        int4 ta = t4[0], tb = t4[1];
        const float4* fc4 = (const float4*)(fcw + j * 8);
        float4 wa = fc4[0], wb = fc4[1];
        float acc = fcb[j]
                  + (float)ta.x * wa.x + (float)ta.y * wa.y
                  + (float)ta.z * wa.z + (float)ta.w * wa.w
                  + (float)tb.x * wb.x + (float)tb.y * wb.y
                  + (float)tb.z * wb.z + (float)tb.w * wb.w;
        out[(size_t)(bb + q) * 96 + j] = fmaxf(acc, 0.f);
      }
    }
    __builtin_amdgcn_wave_barrier();

    if (lane < 32) {
      int j = lane;
      const float4* op4 = (const float4*)(opw + j * 32);
      const float4* S4  = (const float4*)(S + 336);
      f2 av = {opb[j], 0.f};
#pragma unroll 1
      for (int m = 0; m < 8; ++m)
        av = pdot(S4[m], op4[m], av);
      out[(size_t)(bb + q) * 96 + 32 + j] = av.x + av.y;
    }
  }
}

extern "C" void kernel_launch(void* const* d_in, const int* in_sizes, int n_in,
                              void* d_out, int out_size, void* d_ws, size_t ws_size,
                              hipStream_t stream) {
  const int*   t   = (const int*)d_in[0];
  const int*   pt  = (const int*)d_in[1];
  const float* w1  = (const float*)d_in[2];
  const float* b1  = (const float*)d_in[3];
  const float* w2  = (const float*)d_in[4];
  const float* b2w = (const float*)d_in[5];
  const float* w3  = (const float*)d_in[6];
  const float* b3  = (const float*)d_in[7];
  const float* wf1 = (const float*)d_in[8];
  const float* bf1 = (const float*)d_in[9];
  const float* fcw = (const float*)d_in[10];
  const float* fcb = (const float*)d_in[11];
  // d_in[12] = emb : dead (softmax over singleton axis == 1)
  const float* ipw = (const float*)d_in[13];
  const float* ipb = (const float*)d_in[14];
  const float* opw = (const float*)d_in[15];
  const float* opb = (const float*)d_in[16];

  float* out       = (float*)d_out;
  float* out_board = out + (size_t)BATCH * 96;
  float* cbg       = (float*)d_ws;     // WS_TOT floats

  hipLaunchKernelGGL(prep_kernel, dim3(19), dim3(256), 0, stream, w1, b1, w2, cbg);
  hipLaunchKernelGGL(board_model_kernel, dim3(NBLK), dim3(256), 0, stream,
                     t, pt, w1, b1, w2, b2w, w3, b3, wf1, bf1, fcw, fcb,
                     ipw, ipb, opw, opb, cbg, out, out_board);
}